// Round 10
// baseline (95.780 us; speedup 1.0000x reference)
//
#include <hip/hip_runtime.h>
#include <math.h>

// Problem constants (reference: B=16, C=2, H=512, W=512; gt in {0,1})
constexpr int BATCH = 16;
constexpr int H = 512;
constexpr int W = 512;
constexpr int R = 8;        // window radius for vertical scan
constexpr int ROWS = 16;    // output rows per block (window = 32 = one uint)
constexpr int GRID = BATCH * H / ROWS;  // 512 blocks = 2/CU x 256 CU: 1 round
constexpr int PAD = 8;      // ushort pad each side (16 B, keeps b128 alignment)
constexpr int PADW = W + 2 * PAD;       // 528 ushorts = 1056 B row stride
constexpr float INV_N = 1.0f / (float)(16 * 512 * 512);  // mean over B*H*W
constexpr unsigned POISON = 0xAAAAAAAAu;  // harness re-poison pattern for d_ws

// One block per (batch, 16-row group): 512 threads. SINGLE dispatch.
//
// Session facts: same-address atomics = 115us wall (R0-R2); conditional
// loads get serialized (R3); unconditional clamped window loads fix it
// (R4); row-group amortization (R5-R7); 32-bit mask + clz/ffs vertical
// scan (R7); b128 LDS horizontal pass + float4 probs (R8); ushort d1
// (R9, neutral). R10: fuse the reduction — every block publishes its
// partial with an AGENT-scope release store; block 0 spins (AGENT acquire)
// until each slot differs from the 0xAA poison the harness writes before
// every replay (a positive float partial can never equal 0xAAAAAAAA =
// -3e-13). Removes the second dispatch + its launch boundary. Deadlock
// -free: all 512 blocks are co-resident (>=2 blocks/CU) and a spinning
// block never blocks producers. AGENT scope covers cross-XCD L2
// non-coherence.
__global__ __launch_bounds__(512) void boundary_loss_main(
    const float* __restrict__ probs,  // [B, 2, H, W]
    const int* __restrict__ gt,       // [B, 1, H, W]
    float* __restrict__ partial,      // [GRID] in d_ws (poisoned 0xAA)
    float* __restrict__ out)          // [1]
{
    // XCD swizzle: consecutive logical groups (sharing half their gt
    // windows) land on the same XCD (dispatch is round-robin hw % 8).
    const int hw = blockIdx.x;
    const int blk = ((hw & 63) << 3) | (hw >> 6);   // hw 0 -> blk 0
    const int b = blk >> 5;                // 32 groups per batch
    const int i0 = (blk & 31) * ROWS;      // first output row of the group
    const int j = threadIdx.x;             // 0 .. 511

    const int* colp = gt + (size_t)b * (H * W) + j;

    // --- phase 1: pack the clamped 32-row window into one 32-bit mask ---
    unsigned mask = 0;
    {
        int wv[ROWS + 2 * R];
        #pragma unroll
        for (int k = 0; k < ROWS + 2 * R; ++k) {
            int rr = i0 - R + k;
            rr = max(0, min(H - 1, rr));
            wv[k] = colp[rr * W];
        }
        #pragma unroll
        for (int k = 0; k < ROWS + 2 * R; ++k)
            mask |= ((unsigned)wv[k] & 1u) << k;
    }

    __shared__ __align__(16) unsigned short d1s[ROWS][PADW];
    // sentinel pads: 16 rows x 16 slots; threads 0..255 write one each.
    if (j < 256) {
        const int rr = j >> 4, slot = j & 15;
        const int idx = (slot < PAD) ? slot : (W + slot);
        d1s[rr][idx] = 65535u;
    }

    // --- vertical nearest-foreground per row via clz/ffs ---
    #pragma unroll
    for (int r = 0; r < ROWS; ++r) {
        const int ir = i0 + r;
        const int c = R + r;               // bit position (8..23)
        const int up_max = ir;
        const int dn_max = H - 1 - ir;
        const unsigned m_up = mask & ((2u << c) - 1);
        const unsigned m_dn = mask >> c;
        int tu = m_up ? (c - (31 - __clz((int)m_up))) : -1;
        int td = m_dn ? (__ffs((int)m_dn) - 1) : -1;
        // rare fallback: no fg within window reach (P ~ 2^-9/dir)
        if (tu < 0 && up_max > c) {
            int t = c + 1;
            while (tu < 0 && t <= up_max) {
                int v[4];
                #pragma unroll
                for (int k = 0; k < 4; ++k)
                    v[k] = colp[(ir - min(t + k, up_max)) * W];
                #pragma unroll
                for (int k = 0; k < 4; ++k)
                    if (tu < 0 && t + k <= up_max && v[k]) tu = t + k;
                t += 4;
            }
        }
        const int dn_reach = 31 - c;
        if (td < 0 && dn_max > dn_reach) {
            int t = dn_reach + 1;
            while (td < 0 && t <= dn_max) {
                int v[4];
                #pragma unroll
                for (int k = 0; k < 4; ++k)
                    v[k] = colp[(ir + min(t + k, dn_max)) * W];
                #pragma unroll
                for (int k = 0; k < 4; ++k)
                    if (td < 0 && t + k <= dn_max && v[k]) td = t + k;
                t += 4;
            }
        }
        // Reference sentinels (BIG=2*(H+W)=2048) for fg-free half-columns;
        // ushort clamp path unreachable for 50%-dense random gt.
        const int du = (tu >= 0) ? tu * tu : (ir + 2048) * (ir + 2048);
        const int dd = (td >= 0) ? td * td : (2560 - ir) * (2560 - ir);
        d1s[r][PAD + j] = (unsigned short)min(min(du, dd), 65535);
    }
    __syncthreads();

    // --- phase 2: horizontal exact min-plus, 8 columns/thread/task ---
    const float* pbase = probs + (size_t)b * 2 * H * W + (size_t)i0 * W;
    float v = 0.0f;
    #pragma unroll
    for (int pass = 0; pass < 2; ++pass) {
        const int tau = pass * 512 + j;
        const int row = tau >> 6;          // 0..15
        const int jc = (tau & 63) << 3;    // 0..504, multiple of 8
        const unsigned short* drow = d1s[row];
        // padded[jc .. jc+23] = cols jc-8 .. jc+15 (3 aligned b128)
        const int4* qp = (const int4*)(drow + jc);
        const int4 qa = qp[0], qb = qp[1], qc = qp[2];
        int win[24];
        const int raw[12] = {qa.x, qa.y, qa.z, qa.w,
                             qb.x, qb.y, qb.z, qb.w,
                             qc.x, qc.y, qc.z, qc.w};
        #pragma unroll
        for (int k = 0; k < 12; ++k) {
            win[2 * k]     = raw[k] & 0xffff;
            win[2 * k + 1] = ((unsigned)raw[k]) >> 16;
        }
        const float4 pa = *(const float4*)(pbase + (size_t)row * W + jc);
        const float4 pb = *(const float4*)(pbase + (size_t)row * W + jc + 4);
        const float pv[8] = {pa.x, pa.y, pa.z, pa.w, pb.x, pb.y, pb.z, pb.w};
        #pragma unroll
        for (int m = 0; m < 8; ++m) {
            int best = win[8 + m];         // col jc+m
            #pragma unroll
            for (int t = 1; t <= 4; ++t) {
                best = min(best, win[8 + m - t] + t * t);
                best = min(best, win[8 + m + t] + t * t);
            }
            // Rare tail: only if best > 25 can t>=5 still improve.
            if (best > 25) {
                const int c0 = jc + m;
                int t = 5;
                while (t < W && t * t < best) {
                    if (c0 - t >= 0) best = min(best, (int)drow[PAD + c0 - t] + t * t);
                    if (c0 + t <  W) best = min(best, (int)drow[PAD + c0 + t] + t * t);
                    ++t;
                }
            }
            v += pv[m] * sqrtf((float)best);
        }
    }

    // --- block reduction: wave shuffle (64 lanes) then LDS ---
    for (int off = 32; off > 0; off >>= 1)
        v += __shfl_down(v, off, 64);
    __shared__ float wsum[8];
    const int lane = j & 63;
    const int wid = j >> 6;
    if (lane == 0) wsum[wid] = v;
    __syncthreads();
    if (j == 0) {
        float s = 0.0f;
        #pragma unroll
        for (int wi = 0; wi < 8; ++wi) s += wsum[wi];
        // Publish device-wide (AGENT scope release: visible across XCDs).
        __hip_atomic_store((unsigned*)&partial[blk], __float_as_uint(s),
                           __ATOMIC_RELEASE, __HIP_MEMORY_SCOPE_AGENT);
    }

    // --- fused final reduction: block 0 consumes all partials ---
    if (hw == 0) {
        // Thread j spins on slot j until the producer overwrote the 0xAA
        // poison the harness wrote before this launch.
        unsigned u;
        do {
            u = __hip_atomic_load((const unsigned*)&partial[j],
                                  __ATOMIC_ACQUIRE, __HIP_MEMORY_SCOPE_AGENT);
        } while (u == POISON);
        float s = __uint_as_float(u);
        for (int off = 32; off > 0; off >>= 1)
            s += __shfl_down(s, off, 64);
        __shared__ float fsum[8];
        if (lane == 0) fsum[wid] = s;
        __syncthreads();
        if (j == 0) {
            float tot = 0.0f;
            #pragma unroll
            for (int wi = 0; wi < 8; ++wi) tot += fsum[wi];
            out[0] = tot * INV_N;  // single writer overwrites d_out poison
        }
    }
}

extern "C" void kernel_launch(void* const* d_in, const int* in_sizes, int n_in,
                              void* d_out, int out_size, void* d_ws, size_t ws_size,
                              hipStream_t stream) {
    const float* probs = (const float*)d_in[0];
    const int* gt = (const int*)d_in[1];
    float* out = (float*)d_out;
    float* partial = (float*)d_ws;  // 512 floats; harness poisons to 0xAA

    boundary_loss_main<<<dim3(GRID), dim3(512), 0, stream>>>(probs, gt, partial, out);
}

// Round 11
// 88.217 us; speedup vs baseline: 1.0857x; 1.0857x over previous
//
#include <hip/hip_runtime.h>
#include <math.h>

// Problem constants (reference: B=16, C=2, H=512, W=512; gt in {0,1})
constexpr int BATCH = 16;
constexpr int H = 512;
constexpr int W = 512;
constexpr int R = 8;        // window radius for vertical scan
constexpr int ROWS = 16;    // output rows per block (window = 32 = one uint)
constexpr int GRID = BATCH * H / ROWS;  // 512 blocks = 2/CU x 256 CU: 1 round
constexpr int PADW = W + 8; // d1 row padded by 4 sentinels each side
constexpr int BIG = 8000000;  // > max legal best (511+2048)^2 ~ 6.55e6
constexpr float INV_N = 1.0f / (float)(16 * 512 * 512);  // mean over B*H*W

// One block per (batch, 16-row group): 512 threads. Two dispatches.
//
// Session facts: same-address atomics = 115us wall (R0-R2); conditional
// loads get serialized by the compiler (R3, VGPR=8); unconditional clamped
// window loads fix it (R4); row-group amortization works (R5-R7); 32-bit
// mask + clz/ffs vertical scan (R7); b128 LDS horizontal pass + float4
// probs (R8, 88.8us = session best). R9 (ushort d1, half the LDS issue)
// was neutral: phase-2 LDS was no longer a bottleneck after R8. R10
// (fused single-dispatch reduction via poison-spin) REGRESSED +6.6us:
// block 0's spin pays the slowest-block tail inside GPU time; the
// two-dispatch version hides it at the graph level. This is R8 restored.
__global__ __launch_bounds__(512) void boundary_loss_main(
    const float* __restrict__ probs,  // [B, 2, H, W]
    const int* __restrict__ gt,       // [B, 1, H, W]
    float* __restrict__ partial)      // [GRID]
{
    // XCD swizzle: logical = (hw & 63)*8 + (hw >> 6); consecutive logical
    // groups then share an XCD (dispatch is round-robin hw % 8).
    const int hw = blockIdx.x;
    const int blk = ((hw & 63) << 3) | (hw >> 6);
    const int b = blk >> 5;                // 32 groups per batch
    const int i0 = (blk & 31) * ROWS;      // first output row of the group
    const int j = threadIdx.x;             // 0 .. 511

    const int* colp = gt + (size_t)b * (H * W) + j;

    // --- phase 1: pack the clamped 32-row window into one 32-bit mask ---
    int wv[ROWS + 2 * R];
    #pragma unroll
    for (int k = 0; k < ROWS + 2 * R; ++k) {
        int rr = i0 - R + k;
        rr = max(0, min(H - 1, rr));
        wv[k] = colp[rr * W];
    }
    unsigned mask = 0;
    #pragma unroll
    for (int k = 0; k < ROWS + 2 * R; ++k)
        mask |= ((unsigned)wv[k] & 1u) << k;

    __shared__ __align__(16) int d1s[ROWS][PADW];
    // sentinel pads: 16 rows x 8 slots, threads 0..127 write one each
    if (j < 128) {
        const int rr = j >> 3, slot = j & 7;
        const int idx = (slot < 4) ? slot : (W + slot);
        d1s[rr][idx] = BIG;
    }

    // --- vertical nearest-foreground per row via clz/ffs ---
    #pragma unroll
    for (int r = 0; r < ROWS; ++r) {
        const int ir = i0 + r;
        const int c = R + r;               // bit position (8..23)
        const int up_max = ir;
        const int dn_max = H - 1 - ir;
        const unsigned m_up = mask & ((2u << c) - 1);
        const unsigned m_dn = mask >> c;
        int tu = m_up ? (c - (31 - __clz((int)m_up))) : -1;
        int td = m_dn ? (__ffs((int)m_dn) - 1) : -1;
        // rare fallback: no fg within window reach (P ~ 2^-9/dir)
        if (tu < 0 && up_max > c) {
            int t = c + 1;
            while (tu < 0 && t <= up_max) {
                int v[4];
                #pragma unroll
                for (int k = 0; k < 4; ++k)
                    v[k] = colp[(ir - min(t + k, up_max)) * W];
                #pragma unroll
                for (int k = 0; k < 4; ++k)
                    if (tu < 0 && t + k <= up_max && v[k]) tu = t + k;
                t += 4;
            }
        }
        const int dn_reach = 31 - c;
        if (td < 0 && dn_max > dn_reach) {
            int t = dn_reach + 1;
            while (td < 0 && t <= dn_max) {
                int v[4];
                #pragma unroll
                for (int k = 0; k < 4; ++k)
                    v[k] = colp[(ir + min(t + k, dn_max)) * W];
                #pragma unroll
                for (int k = 0; k < 4; ++k)
                    if (td < 0 && t + k <= dn_max && v[k]) td = t + k;
                t += 4;
            }
        }
        // Reference sentinels (BIG=2*(H+W)=2048) for fg-free half-columns:
        const int du = (tu >= 0) ? tu * tu : (ir + 2048) * (ir + 2048);
        const int dd = (td >= 0) ? td * td : (2560 - ir) * (2560 - ir);
        d1s[r][4 + j] = min(du, dd);
    }
    __syncthreads();

    // --- phase 2: horizontal exact min-plus, 4 columns/thread/task ---
    // tasks: 16 rows x 128 col-quads = 2048; 4 passes of 512 threads.
    const float* pbase = probs + (size_t)b * 2 * H * W + (size_t)i0 * W;
    float v = 0.0f;
    #pragma unroll
    for (int pass = 0; pass < 4; ++pass) {
        const int tau = pass * 512 + j;
        const int row = tau >> 7;          // 0..15
        const int jc = (tau & 127) << 2;   // 0..508, multiple of 4
        const int* drow = d1s[row];
        const int4* qp = (const int4*)(drow + jc);  // 16B aligned
        const int4 qa = qp[0], qb = qp[1], qc = qp[2];
        const int win[12] = {qa.x, qa.y, qa.z, qa.w,
                             qb.x, qb.y, qb.z, qb.w,
                             qc.x, qc.y, qc.z, qc.w};
        const float4 p4 = *(const float4*)(pbase + (size_t)row * W + jc);
        const float pv[4] = {p4.x, p4.y, p4.z, p4.w};
        #pragma unroll
        for (int m = 0; m < 4; ++m) {
            int best = win[4 + m];
            #pragma unroll
            for (int t = 1; t <= 4; ++t) {
                best = min(best, win[4 + m - t] + t * t);
                best = min(best, win[4 + m + t] + t * t);
            }
            // Rare tail: only if best > 25 can t>=5 still improve.
            if (best > 25) {
                const int c0 = jc + m;
                int t = 5;
                while (t < W && t * t < best) {
                    if (c0 - t >= 0) best = min(best, drow[4 + c0 - t] + t * t);
                    if (c0 + t <  W) best = min(best, drow[4 + c0 + t] + t * t);
                    ++t;
                }
            }
            v += pv[m] * sqrtf((float)best);
        }
    }

    // --- block reduction: wave shuffle (64 lanes) then LDS ---
    for (int off = 32; off > 0; off >>= 1)
        v += __shfl_down(v, off, 64);
    __shared__ float wsum[8];
    const int lane = j & 63;
    const int wid = j >> 6;
    if (lane == 0) wsum[wid] = v;
    __syncthreads();
    if (j == 0) {
        float s = 0.0f;
        #pragma unroll
        for (int wi = 0; wi < 8; ++wi) s += wsum[wi];
        partial[blk] = s;   // plain store, no contention
    }
}

// Single-block tail: reduce 512 partials, scale, write the scalar output.
__global__ __launch_bounds__(512) void boundary_loss_reduce(
    const float* __restrict__ partial,  // [GRID]
    float* __restrict__ out)            // [1]
{
    const int j = threadIdx.x;
    float s = (j < GRID) ? partial[j] : 0.0f;
    for (int off = 32; off > 0; off >>= 1)
        s += __shfl_down(s, off, 64);
    __shared__ float wsum[8];
    const int lane = j & 63;
    const int wid = j >> 6;
    if (lane == 0) wsum[wid] = s;
    __syncthreads();
    if (j == 0) {
        float tot = 0.0f;
        #pragma unroll
        for (int wi = 0; wi < 8; ++wi) tot += wsum[wi];
        out[0] = tot * INV_N;   // single writer overwrites poison; no memset needed
    }
}

extern "C" void kernel_launch(void* const* d_in, const int* in_sizes, int n_in,
                              void* d_out, int out_size, void* d_ws, size_t ws_size,
                              hipStream_t stream) {
    const float* probs = (const float*)d_in[0];
    const int* gt = (const int*)d_in[1];
    float* out = (float*)d_out;
    float* partial = (float*)d_ws;  // 512 floats = 2 KB scratch

    boundary_loss_main<<<dim3(GRID), dim3(512), 0, stream>>>(probs, gt, partial);
    boundary_loss_reduce<<<dim3(1), dim3(512), 0, stream>>>(partial, out);
}